// Round 8
// baseline (68.100 us; speedup 1.0000x reference)
//
#include <hip/hip_runtime.h>

// Batched Thomas tridiagonal solve, B=8192 rows, N=4096.
//   a_i = alpha[i-1]^2 (a_0=0); b_i = max(5+alpha[i]^3, 0.01);
//   c_i = alpha[i+1]^2 + 2*alpha[i+1]; rhs f (shared across rows).
//
// Chunked UL elimination with halos (diag dominant: right halo 32, left 8).
//
// R8: true async staging. R7's reg-staged prefetch was sunk by the register
// allocator (VGPR_Count=80 < live set). Replace with global_load_lds width=16
// (no VGPR dest, unsinkable) + LDS double buffer + counted vmcnt pipeline:
// 1-wave blocks, 8 tiles (256 cols each) per wave, prefetch t+2 during t.
// Waits exact: 12 loads + 8 stores per tile, in-order vmcnt retirement ->
// vmcnt(12) @t=0, vmcnt(20) @t=1..6, vmcnt(8) @t=7. LDS 21.9KB -> 7 waves/CU.
// Solve math identical to R7 (absmax anchor 0.00390625).

namespace {
constexpr int kCH  = 32;             // outputs per lane
constexpr int kHL  = 8;              // left halo
constexpr int kR   = kCH + kHL;      // stored region = 40
constexpr int RPW  = 8;              // rows per wave
constexpr int F4PR = 76;             // staged f4/row: cols [cb-12, cb+292)
constexpr int APAN = RPW * F4PR;     // 608 f4 per A buffer (linear, no pad)
}

__device__ __forceinline__ void glds16(const float4* g, float4* l) {
  __builtin_amdgcn_global_load_lds(
      (const __attribute__((address_space(1))) unsigned int*)g,
      (__attribute__((address_space(3))) unsigned int*)l, 16, 0, 0);
}

__global__ __launch_bounds__(64) void thomas_v8(
    const float4* __restrict__ alpha4,
    const float4* __restrict__ f4,
    float4* __restrict__ u4)
{
  __shared__ float4 sA[2 * APAN];    // two linear A panels [8][76]
  __shared__ float4 sF[2 * F4PR];    // two f windows

  const int bid  = blockIdx.x;
  const int half = bid & 1;                    // 0: cols 0-2047, 1: 2048-4095
  const int rw0  = (bid >> 1) * RPW;           // first row of this wave
  const int lane = threadIdx.x;                // 0..63
  const int j    = lane & 7;                   // row-local
  const int q    = lane >> 3;                  // chunk-local 0..7

  // per-batch (row, c4) and row pointers: batch it, lane l -> idx = it*64+l,
  // row = idx/76, c4 = idx%76.  Linear LDS dest = idx (global_load_lds order).
  const float4* rowp[10];
  int c4t[10];
  #pragma unroll
  for (int it = 0; it < 10; ++it) {
    const int idx = it * 64 + lane;
    int row = idx / F4PR;
    if (row > 7) row = 7;                      // it=9 masked lanes: harmless
    c4t[it] = idx - row * F4PR;
    rowp[it] = alpha4 + (size_t)(rw0 + row) * 1024;
  }

#define PREFETCH(TT, AB, FB)                                              \
  {                                                                       \
    const int cb4_ = (half * 8 + (TT)) * 64 - 3;                          \
    _Pragma("unroll")                                                     \
    for (int it = 0; it < 9; ++it) {                                      \
      int g4 = cb4_ + c4t[it];                                            \
      g4 = (g4 < 0) ? 0 : ((g4 > 1023) ? 1023 : g4);   /* dups unused */  \
      glds16(rowp[it] + g4, (AB) + it * 64);                              \
    }                                                                     \
    if (lane < 32) {                                  /* idx 576..607 */  \
      int g4 = cb4_ + c4t[9];                                             \
      g4 = (g4 < 0) ? 0 : ((g4 > 1023) ? 1023 : g4);                      \
      glds16(rowp[9] + g4, (AB) + 9 * 64);                                \
    }                                                                     \
    {                                                                     \
      int gf = cb4_ + lane;                                               \
      gf = (gf < 0) ? 0 : ((gf > 1023) ? 1023 : gf);                      \
      glds16(f4 + gf, (FB));                                              \
    }                                                                     \
    if (lane < 12) {                                                      \
      int gf = cb4_ + 64 + lane;                                          \
      gf = (gf > 1023) ? 1023 : gf;                                       \
      glds16(f4 + gf, (FB) + 64);                                         \
    }                                                                     \
  }   /* 12 vmcnt ops per PREFETCH */

#define STEP(am1v, fiv)                                        \
  {                                                            \
    const float c_  = ap1 * (ap1 + 2.0f);                      \
    const float b_  = fmaxf(fmaf(a0 * a0, a0, 5.0f), 0.01f);   \
    const float dn  = fmaf(-c_, ec, b_);                       \
    const float rd  = __builtin_amdgcn_rcpf(dn);               \
    gc = (fiv - c_ * gc) * rd;                                 \
    ec = ((am1v) * (am1v)) * rd;                               \
    ap1 = a0; a0 = (am1v);                                     \
  }

#define SOLVE_TILE(TT, AB, FB)                                            \
  {                                                                       \
    const int  cw_   = half * 8 + (TT);                                   \
    const int  kk    = cw_ * 8 + q;                                       \
    const bool first = (kk == 0);                                         \
    const bool last  = (kk == 127);                                       \
    const int  f4b   = first ? 3 : (q * 8 + 1);                           \
    const float4* __restrict__ A4 = (AB) + j * F4PR;                      \
    const float4* __restrict__ Fb = (FB);                                 \
    float gp[kR], ep[kR];                                                 \
    float ec = 0.0f, gc = 0.0f, ap1 = 0.0f;                               \
    const int ghi = last ? 9 : 17;                                        \
    float4 curA = A4[f4b + ghi];                                          \
    float4 lowA = A4[f4b + ghi - 1];                                      \
    float4 fcur = Fb[f4b + ghi];                                          \
    float4 flow = Fb[f4b + ghi - 1];                                      \
    float a0 = curA.w;                                                    \
    if (!last) {                                                          \
      _Pragma("unroll")                                                   \
      for (int g = 17; g >= 10; --g) {                                    \
        const float4 pA = A4[f4b + g - 2];                                \
        const float4 pF = Fb[f4b + g - 2];                                \
        STEP(curA.z, fcur.w)                                              \
        STEP(curA.y, fcur.z)                                              \
        STEP(curA.x, fcur.y)                                              \
        STEP(lowA.w, fcur.x)                                              \
        curA = lowA; lowA = pA; fcur = flow; flow = pF;                   \
      }                                                                   \
    }                                                                     \
    _Pragma("unroll")                                                     \
    for (int g = 9; g >= 0; --g) {                                        \
      int pidx = f4b + g - 2;                                             \
      if (pidx < 0) pidx = 0;            /* value unused when clamped */  \
      const float4 pA = A4[pidx];                                         \
      const float4 pF = Fb[pidx];                                         \
      float lw = lowA.w;                                                  \
      if (g == 0 && first) lw = 0.0f;    /* a_0 = 0 */                    \
      STEP(curA.z, fcur.w)  gp[4*g+3] = gc; ep[4*g+3] = ec;               \
      STEP(curA.y, fcur.z)  gp[4*g+2] = gc; ep[4*g+2] = ec;               \
      STEP(curA.x, fcur.y)  gp[4*g+1] = gc; ep[4*g+1] = ec;               \
      STEP(lw,     fcur.x)  gp[4*g+0] = gc; ep[4*g+0] = ec;               \
      curA = lowA; lowA = pA; fcur = flow; flow = pF;                     \
    }                                                                     \
    const int tmin = first ? 0 : kHL;                                     \
    float up = 0.0f;                                                      \
    float4 pk;                                                            \
    _Pragma("unroll")                                                     \
    for (int t_ = 0; t_ < kR; ++t_) {                                     \
      const float uv = fmaf(-ep[t_], up, gp[t_]);                         \
      up = uv;                                                            \
      const int ph = t_ & 3;                                              \
      if      (ph == 0) pk.x = uv;                                        \
      else if (ph == 1) pk.y = uv;                                        \
      else if (ph == 2) pk.z = uv;                                        \
      else {                                                              \
        pk.w = uv;                                                        \
        if (t_ - 3 >= tmin && t_ < tmin + kCH) {                          \
          (AB)[j * F4PR + q * 8 + ((t_ - 3 - tmin) >> 2)] = pk;           \
        }                                                                 \
      }                                                                   \
    }                                                                     \
    _Pragma("unroll")                                                     \
    for (int rr = 0; rr < RPW; ++rr) {                                    \
      const float4 v = (AB)[rr * F4PR + lane];                            \
      u4[(size_t)(rw0 + rr) * 1024 + cw_ * 64 + lane] = v;                \
    }                                                                     \
  }   /* 8 vmcnt stores per SOLVE_TILE dump */

  // ---- prologue: fill both buffers ----
  PREFETCH(0, sA, sF)
  PREFETCH(1, sA + APAN, sF + F4PR)

  // ---- pipelined tile loop ----
  #pragma unroll 1
  for (int t = 0; t < 8; ++t) {
    float4* ab = (t & 1) ? (sA + APAN) : sA;
    float4* fb = (t & 1) ? (sF + F4PR) : sF;
    // exact in-order vmcnt: outstanding after L(t) completes:
    //   t=0: L1(12);  t=1..6: S(t-1)(8)+L(t+1)(12)=20;  t=7: S6(8)
    if (t == 0)      asm volatile("s_waitcnt vmcnt(12)" ::: "memory");
    else if (t == 7) asm volatile("s_waitcnt vmcnt(8)"  ::: "memory");
    else             asm volatile("s_waitcnt vmcnt(20)" ::: "memory");
    SOLVE_TILE(t, ab, fb)
    asm volatile("s_waitcnt lgkmcnt(0)" ::: "memory");  // drain ds ops on ab/fb
    if (t < 6) PREFETCH(t + 2, ab, fb)
  }

#undef PREFETCH
#undef STEP
#undef SOLVE_TILE
}

extern "C" void kernel_launch(void* const* d_in, const int* in_sizes, int n_in,
                              void* d_out, int out_size, void* d_ws, size_t ws_size,
                              hipStream_t stream) {
  const float4* alpha = (const float4*)d_in[0];
  const float4* f     = (const float4*)d_in[1];
  float4*       uo    = (float4*)d_out;
  // grid: 1024 row-strips (8 rows) x 2 col-halves = 2048 one-wave blocks
  thomas_v8<<<dim3(2048), 64, 0, stream>>>(alpha, f, uo);
}

// Round 9
// 54.776 us; speedup vs baseline: 1.2432x; 1.2432x over previous
//
#include <hip/hip_runtime.h>

// Batched Thomas tridiagonal solve, B=8192 rows, N=4096.
//   a_i = alpha[i-1]^2 (a_0=0); b_i = max(5+alpha[i]^3, 0.01);
//   c_i = alpha[i+1]^2 + 2*alpha[i+1]; rhs f (shared across rows).
//
// Chunked UL elimination with halos (diag dominant: backward decay <=0.70/step
// -> right halo H=32 err ~1e-5; forward decay <=0.235/step -> left halo HL=8).
//
// R9: R7 + anti-sink fence. R7's VGPR_Count=80 proved the p1 prefetch loads
// were sunk to their use (no latency hiding). asm memory-clobber fence after
// LOAD_TILE(p1) forbids the sink; __launch_bounds__(128,3) raises the VGPR
// cap to ~170 so the 40 pinned regs don't spill. Everything else identical
// to R7 (absmax anchor 0.00390625). R8's 1-wave/global_load_lds variant
// regressed (occupancy 13.5%) and is abandoned.

namespace {
constexpr int kN   = 4096;
constexpr int kCH  = 32;              // outputs per lane
constexpr int kHL  = 8;               // left halo
constexpr int kR   = kCH + kHL;       // stored region = 40
constexpr int kNC  = kN / kCH;        // 128 chunks per row
constexpr int RPW  = 8;               // rows per wave
constexpr int WAVES = 2;
constexpr int THREADS = 64 * WAVES;   // 128
constexpr int F4PR = 76;              // per-tile staged f4/row: [cb-12, cb+292)
constexpr int ST4  = 77;              // A row stride in f4 (308 dw; %32==20)
constexpr int APW4 = RPW * ST4;       // 616 f4 per wave A panel
constexpr int SF4  = 141;             // shared f window: 140 f4 + pad
}

__global__ __launch_bounds__(THREADS, 3) void thomas_v9(
    const float4* __restrict__ alpha4,
    const float4* __restrict__ f4,
    float4* __restrict__ u4)
{
  __shared__ float4 sM[WAVES * APW4 + SF4];   // 1373 f4 = 21968 B

  const int bid  = blockIdx.x;
  const int pair = bid & 7;                     // 512-col window pair
  const int r0   = (bid >> 3) * (WAVES * RPW);
  const int w    = threadIdx.x >> 6;
  const int lane = threadIdx.x & 63;
  const int rw0  = r0 + w * RPW;
  const int j    = lane & 7;                    // row-local (quarter-wave: 8 rows)
  const int q    = lane >> 3;                   // chunk-local 0..7

  float4* __restrict__ sA = sM + w * APW4;      // wave-private [RPW][ST4]
  float4* __restrict__ sF = sM + WAVES * APW4;  // block-shared f pair window

#define LOAD_TILE(cw, P)                                              \
  {                                                                   \
    const int cb4 = (cw) * 64 - 3;                                    \
    _Pragma("unroll")                                                 \
    for (int it = 0; it < 10; ++it) {                                 \
      int idx = lane + it * 64;                                       \
      if (idx > RPW * F4PR - 1) idx = RPW * F4PR - 1;  /* dup */      \
      const int row = idx / F4PR;                                     \
      const int c4  = idx - row * F4PR;                               \
      int g4 = cb4 + c4;                                              \
      g4 = (g4 < 0) ? 0 : ((g4 > 1023) ? 1023 : g4);  /* dups unused */ \
      P[it] = alpha4[(size_t)(rw0 + row) * 1024 + g4];                \
    }                                                                 \
  }

#define WRITE_TILE(P)                                                 \
  {                                                                   \
    _Pragma("unroll")                                                 \
    for (int it = 0; it < 10; ++it) {                                 \
      const int idx = lane + it * 64;                                 \
      if (idx < RPW * F4PR) {                                         \
        const int row = idx / F4PR;                                   \
        const int c4  = idx - row * F4PR;                             \
        sA[row * ST4 + c4] = P[it];                                   \
      }                                                               \
    }                                                                 \
  }

#define STEP(am1v, fiv)                                        \
  {                                                            \
    const float c_  = ap1 * (ap1 + 2.0f);                      \
    const float b_  = fmaxf(fmaf(a0 * a0, a0, 5.0f), 0.01f);   \
    const float dn  = fmaf(-c_, ec, b_);                       \
    const float rd  = __builtin_amdgcn_rcpf(dn);               \
    gc = (fiv - c_ * gc) * rd;                                 \
    ec = ((am1v) * (am1v)) * rd;                               \
    ap1 = a0; a0 = (am1v);                                     \
  }

  // Solve one tile from sA/sF; CWL is a compile-time 0/1.
#define SOLVE_TILE(CWL)                                                   \
  {                                                                       \
    const int  kk    = (pair * 2 + (CWL)) * 8 + q;                        \
    const bool first = (kk == 0);                                         \
    const bool last  = (kk == kNC - 1);                                   \
    const int  f4b   = first ? 3 : (q * 8 + 1);                           \
    const int  fOff  = (CWL) * 64;                                        \
    const float4* __restrict__ A4 = sA + j * ST4;                         \
    float gp[kR], ep[kR];                                                 \
    float ec = 0.0f, gc = 0.0f, ap1 = 0.0f;                               \
    const int ghi = last ? 9 : 17;                                        \
    float4 curA = A4[f4b + ghi];                                          \
    float4 lowA = A4[f4b + ghi - 1];                                      \
    float4 fcur = sF[fOff + f4b + ghi];                                   \
    float4 flow = sF[fOff + f4b + ghi - 1];                               \
    float a0 = curA.w;                                                    \
    if (!last) {                                                          \
      _Pragma("unroll")                                                   \
      for (int g = 17; g >= 10; --g) {                                    \
        const float4 pA = A4[f4b + g - 2];                                \
        const float4 pF = sF[fOff + f4b + g - 2];                         \
        STEP(curA.z, fcur.w)                                              \
        STEP(curA.y, fcur.z)                                              \
        STEP(curA.x, fcur.y)                                              \
        STEP(lowA.w, fcur.x)                                              \
        curA = lowA; lowA = pA; fcur = flow; flow = pF;                   \
      }                                                                   \
    }                                                                     \
    _Pragma("unroll")                                                     \
    for (int g = 9; g >= 0; --g) {                                        \
      int pidx = f4b + g - 2;                                             \
      if (pidx < 0) pidx = 0;            /* value unused when clamped */  \
      const float4 pA = A4[pidx];                                         \
      const float4 pF = sF[fOff + pidx];                                  \
      float lw = lowA.w;                                                  \
      if (g == 0 && first) lw = 0.0f;    /* a_0 = 0 */                    \
      STEP(curA.z, fcur.w)  gp[4*g+3] = gc; ep[4*g+3] = ec;               \
      STEP(curA.y, fcur.z)  gp[4*g+2] = gc; ep[4*g+2] = ec;               \
      STEP(curA.x, fcur.y)  gp[4*g+1] = gc; ep[4*g+1] = ec;               \
      STEP(lw,     fcur.x)  gp[4*g+0] = gc; ep[4*g+0] = ec;               \
      curA = lowA; lowA = pA; fcur = flow; flow = pF;                     \
    }                                                                     \
    const int tmin = first ? 0 : kHL;                                     \
    float up = 0.0f;                                                      \
    float4 pk;                                                            \
    _Pragma("unroll")                                                     \
    for (int t = 0; t < kR; ++t) {                                        \
      const float uv = fmaf(-ep[t], up, gp[t]);                           \
      up = uv;                                                            \
      const int ph = t & 3;                                               \
      if      (ph == 0) pk.x = uv;                                        \
      else if (ph == 1) pk.y = uv;                                        \
      else if (ph == 2) pk.z = uv;                                        \
      else {                                                              \
        pk.w = uv;                                                        \
        if (t - 3 >= tmin && t < tmin + kCH) {                            \
          sA[j * ST4 + q * 8 + ((t - 3 - tmin) >> 2)] = pk;               \
        }                                                                 \
      }                                                                   \
    }                                                                     \
    _Pragma("unroll")                                                     \
    for (int it = 0; it < RPW; ++it) {                                    \
      const float4 v = sA[it * ST4 + lane];                               \
      u4[(size_t)(rw0 + it) * 1024 + (pair * 2 + (CWL)) * 64 + lane] = v; \
    }                                                                     \
  }

  // ---- shared f window (idempotent writes by both waves; no barrier) ----
  {
    const int fb4 = pair * 128 - 3;
    #pragma unroll
    for (int it = 0; it < 3; ++it) {
      const int idx = lane + it * 64;
      if (idx < 140) {
        int g4 = fb4 + idx;
        g4 = (g4 < 0) ? 0 : ((g4 > 1023) ? 1023 : g4);
        sF[idx] = f4[g4];
      }
    }
  }

  // ---- two-tile pipeline with pinned prefetch ----
  float4 p0[10];
  LOAD_TILE(pair * 2, p0)
  WRITE_TILE(p0)

  float4 p1[10];
  LOAD_TILE(pair * 2 + 1, p1)   // issued BEFORE T0 compute
  // Anti-sink fence: a memory read may not be reordered past a
  // memory-clobbering asm, so the 10 loads above must be issued here,
  // overlapping SOLVE_TILE(0). Their s_waitcnt lands at WRITE_TILE(p1).
  asm volatile("" ::: "memory");

  SOLVE_TILE(0)                 // compute + subst + dump T0 (~1400 cyc cover)

  WRITE_TILE(p1)                // vmcnt wait for p1 here (count-precise pass)

  SOLVE_TILE(1)

#undef LOAD_TILE
#undef WRITE_TILE
#undef STEP
#undef SOLVE_TILE
}

extern "C" void kernel_launch(void* const* d_in, const int* in_sizes, int n_in,
                              void* d_out, int out_size, void* d_ws, size_t ws_size,
                              hipStream_t stream) {
  const float4* alpha = (const float4*)d_in[0];
  const float4* f     = (const float4*)d_in[1];
  float4*       uo    = (float4*)d_out;
  // grid: 512 row-groups (16 rows) x 8 window-pairs (512 cols) = 4096 blocks
  thomas_v9<<<dim3(4096), THREADS, 0, stream>>>(alpha, f, uo);
}

// Round 10
// 51.787 us; speedup vs baseline: 1.3150x; 1.0577x over previous
//
#include <hip/hip_runtime.h>

// Batched Thomas tridiagonal solve, B=8192 rows, N=4096.
//   a_i = alpha[i-1]^2 (a_0=0); b_i = max(5+alpha[i]^3, 0.01);
//   c_i = alpha[i+1]^2 + 2*alpha[i+1]; rhs f (shared across rows).
//
// Chunked UL elimination with halos. Carry-gain bound: d(ec)/d(ec_prev) =
// a^2*c/dn^2 <= 3/4.3^2 = 0.162 -> right halo H=8 worst-case err 5e-7.
// Subst decay |ep| <= 1/4.3 = 0.233 -> left halo HL=8 err 8e-6. Thr 2.25e-2.
//
// R10: H 32->8. R9 showed occupancy reg-capped at 2 waves/SIMD (arrays in
// unified AGPRs); halo was 4x oversized (0.70/step bound was wrong, 0.162
// correct). Steps/tile 576->384 (-33% VALU), panel 76->69 f4/row, LDS
// 22.0->19.8 KB. Everything else identical to R9.

namespace {
constexpr int kN   = 4096;
constexpr int kCH  = 32;              // outputs per lane
constexpr int kHL  = 8;               // left halo
constexpr int kR   = kCH + kHL;       // stored region = 40 (groups 0..9)
constexpr int kNC  = kN / kCH;        // 128 chunks per row
constexpr int RPW  = 8;               // rows per wave
constexpr int WAVES = 2;
constexpr int THREADS = 64 * WAVES;   // 128
constexpr int F4PR = 69;              // staged f4/row: cols [cb-12, cb+264)
constexpr int ST4  = 71;              // A row stride in f4 (284 dw; %32==28)
constexpr int APW4 = RPW * ST4;       // 568 f4 per wave A panel
constexpr int SF4  = 133;             // shared f pair window (idx 0..132)
constexpr int GHI  = 11;              // top group (halo groups 10..11)
}

__global__ __launch_bounds__(THREADS, 3) void thomas_v10(
    const float4* __restrict__ alpha4,
    const float4* __restrict__ f4,
    float4* __restrict__ u4)
{
  __shared__ float4 sM[WAVES * APW4 + SF4];   // 1269 f4 = 20304 B

  const int bid  = blockIdx.x;
  const int pair = bid & 7;                     // 512-col window pair
  const int r0   = (bid >> 3) * (WAVES * RPW);
  const int w    = threadIdx.x >> 6;
  const int lane = threadIdx.x & 63;
  const int rw0  = r0 + w * RPW;
  const int j    = lane & 7;                    // row-local (quarter-wave: 8 rows)
  const int q    = lane >> 3;                   // chunk-local 0..7

  float4* __restrict__ sA = sM + w * APW4;      // wave-private [RPW][ST4]
  float4* __restrict__ sF = sM + WAVES * APW4;  // block-shared f pair window

#define LOAD_TILE(cw, P)                                              \
  {                                                                   \
    const int cb4 = (cw) * 64 - 3;                                    \
    _Pragma("unroll")                                                 \
    for (int it = 0; it < 9; ++it) {                                  \
      int idx = lane + it * 64;                                       \
      if (idx > RPW * F4PR - 1) idx = RPW * F4PR - 1;  /* dup */      \
      const int row = idx / F4PR;                                     \
      const int c4  = idx - row * F4PR;                               \
      int g4 = cb4 + c4;                                              \
      g4 = (g4 < 0) ? 0 : ((g4 > 1023) ? 1023 : g4);  /* dups unused */ \
      P[it] = alpha4[(size_t)(rw0 + row) * 1024 + g4];                \
    }                                                                 \
  }

#define WRITE_TILE(P)                                                 \
  {                                                                   \
    _Pragma("unroll")                                                 \
    for (int it = 0; it < 9; ++it) {                                  \
      const int idx = lane + it * 64;                                 \
      if (idx < RPW * F4PR) {                                         \
        const int row = idx / F4PR;                                   \
        const int c4  = idx - row * F4PR;                             \
        sA[row * ST4 + c4] = P[it];                                   \
      }                                                               \
    }                                                                 \
  }

#define STEP(am1v, fiv)                                        \
  {                                                            \
    const float c_  = ap1 * (ap1 + 2.0f);                      \
    const float b_  = fmaxf(fmaf(a0 * a0, a0, 5.0f), 0.01f);   \
    const float dn  = fmaf(-c_, ec, b_);                       \
    const float rd  = __builtin_amdgcn_rcpf(dn);               \
    gc = (fiv - c_ * gc) * rd;                                 \
    ec = ((am1v) * (am1v)) * rd;                               \
    ap1 = a0; a0 = (am1v);                                     \
  }

  // Solve one tile from sA/sF; CWL is a compile-time 0/1.
#define SOLVE_TILE(CWL)                                                   \
  {                                                                       \
    const int  kk    = (pair * 2 + (CWL)) * 8 + q;                        \
    const bool first = (kk == 0);                                         \
    const bool last  = (kk == kNC - 1);                                   \
    const int  f4b   = first ? 3 : (q * 8 + 1);                           \
    const int  fOff  = (CWL) * 64;                                        \
    const float4* __restrict__ A4 = sA + j * ST4;                         \
    float gp[kR], ep[kR];                                                 \
    float ec = 0.0f, gc = 0.0f, ap1 = 0.0f;                               \
    const int ghi = last ? 9 : GHI;                                       \
    float4 curA = A4[f4b + ghi];                                          \
    float4 lowA = A4[f4b + ghi - 1];                                      \
    float4 fcur = sF[fOff + f4b + ghi];                                   \
    float4 flow = sF[fOff + f4b + ghi - 1];                               \
    float a0 = curA.w;                                                    \
    if (!last) {                                                          \
      _Pragma("unroll")                                                   \
      for (int g = GHI; g >= 10; --g) {                                   \
        const float4 pA = A4[f4b + g - 2];                                \
        const float4 pF = sF[fOff + f4b + g - 2];                         \
        STEP(curA.z, fcur.w)                                              \
        STEP(curA.y, fcur.z)                                              \
        STEP(curA.x, fcur.y)                                              \
        STEP(lowA.w, fcur.x)                                              \
        curA = lowA; lowA = pA; fcur = flow; flow = pF;                   \
      }                                                                   \
    }                                                                     \
    _Pragma("unroll")                                                     \
    for (int g = 9; g >= 0; --g) {                                        \
      int pidx = f4b + g - 2;                                             \
      if (pidx < 0) pidx = 0;            /* value unused when clamped */  \
      const float4 pA = A4[pidx];                                         \
      const float4 pF = sF[fOff + pidx];                                  \
      float lw = lowA.w;                                                  \
      if (g == 0 && first) lw = 0.0f;    /* a_0 = 0 */                    \
      STEP(curA.z, fcur.w)  gp[4*g+3] = gc; ep[4*g+3] = ec;               \
      STEP(curA.y, fcur.z)  gp[4*g+2] = gc; ep[4*g+2] = ec;               \
      STEP(curA.x, fcur.y)  gp[4*g+1] = gc; ep[4*g+1] = ec;               \
      STEP(lw,     fcur.x)  gp[4*g+0] = gc; ep[4*g+0] = ec;               \
      curA = lowA; lowA = pA; fcur = flow; flow = pF;                     \
    }                                                                     \
    const int tmin = first ? 0 : kHL;                                     \
    float up = 0.0f;                                                      \
    float4 pk;                                                            \
    _Pragma("unroll")                                                     \
    for (int t = 0; t < kR; ++t) {                                        \
      const float uv = fmaf(-ep[t], up, gp[t]);                           \
      up = uv;                                                            \
      const int ph = t & 3;                                               \
      if      (ph == 0) pk.x = uv;                                        \
      else if (ph == 1) pk.y = uv;                                        \
      else if (ph == 2) pk.z = uv;                                        \
      else {                                                              \
        pk.w = uv;                                                        \
        if (t - 3 >= tmin && t < tmin + kCH) {                            \
          sA[j * ST4 + q * 8 + ((t - 3 - tmin) >> 2)] = pk;               \
        }                                                                 \
      }                                                                   \
    }                                                                     \
    _Pragma("unroll")                                                     \
    for (int it = 0; it < RPW; ++it) {                                    \
      const float4 v = sA[it * ST4 + lane];                               \
      u4[(size_t)(rw0 + it) * 1024 + (pair * 2 + (CWL)) * 64 + lane] = v; \
    }                                                                     \
  }

  // ---- shared f window (idempotent writes by both waves; no barrier) ----
  {
    const int fb4 = pair * 128 - 3;
    #pragma unroll
    for (int it = 0; it < 3; ++it) {
      const int idx = lane + it * 64;
      if (idx < SF4) {
        int g4 = fb4 + idx;
        g4 = (g4 < 0) ? 0 : ((g4 > 1023) ? 1023 : g4);
        sF[idx] = f4[g4];
      }
    }
  }

  // ---- two-tile pipeline with pinned prefetch ----
  float4 p0[9];
  LOAD_TILE(pair * 2, p0)
  WRITE_TILE(p0)

  float4 p1[9];
  LOAD_TILE(pair * 2 + 1, p1)   // issued BEFORE T0 compute
  asm volatile("" ::: "memory"); // anti-sink fence

  SOLVE_TILE(0)                 // compute + subst + dump T0

  WRITE_TILE(p1)                // vmcnt wait for p1 lands here

  SOLVE_TILE(1)

#undef LOAD_TILE
#undef WRITE_TILE
#undef STEP
#undef SOLVE_TILE
}

extern "C" void kernel_launch(void* const* d_in, const int* in_sizes, int n_in,
                              void* d_out, int out_size, void* d_ws, size_t ws_size,
                              hipStream_t stream) {
  const float4* alpha = (const float4*)d_in[0];
  const float4* f     = (const float4*)d_in[1];
  float4*       uo    = (float4*)d_out;
  // grid: 512 row-groups (16 rows) x 8 window-pairs (512 cols) = 4096 blocks
  thomas_v10<<<dim3(4096), THREADS, 0, stream>>>(alpha, f, uo);
}